// Round 3
// baseline (911.112 us; speedup 1.0000x reference)
//
#include <hip/hip_runtime.h>
#include <hip/hip_bf16.h>
#include <math.h>

#define N_NODES 100000
#define N_EDGES 800000
#define IN_C 96
#define OUT_C 64
#define NPB 64   // nodes per block in linear kernel

// ================= CSR build =================

__global__ void zero_int_kernel(int* __restrict__ p, int n) {
    int i = blockIdx.x * blockDim.x + threadIdx.x;
    if (i < n) p[i] = 0;
}

__global__ void count_kernel(const int* __restrict__ col, int* __restrict__ cnt, int e) {
    int i = blockIdx.x * blockDim.x + threadIdx.x;
    if (i < e) atomicAdd(&cnt[col[i]], 1);
}

__global__ void dinv_kernel(const int* __restrict__ cnt, float* __restrict__ dinv, int n) {
    int i = blockIdx.x * blockDim.x + threadIdx.x;
    if (i < n) dinv[i] = rsqrtf((float)cnt[i] + 1.0f);
}

__global__ void scan_pass1_kernel(const int* __restrict__ cnt, int* __restrict__ partials, int n) {
    __shared__ int s[256];
    int i = blockIdx.x * 256 + threadIdx.x;
    int v = (i < n) ? cnt[i] : 0;
    s[threadIdx.x] = v;
    __syncthreads();
    for (int off = 128; off > 0; off >>= 1) {
        if (threadIdx.x < off) s[threadIdx.x] += s[threadIdx.x + off];
        __syncthreads();
    }
    if (threadIdx.x == 0) partials[blockIdx.x] = s[0];
}

__global__ void scan_pass2_kernel(int* __restrict__ partials, int* __restrict__ row_start,
                                  int nparts, int n_nodes) {
    __shared__ int s[512];
    int t = threadIdx.x;
    int v = (t < nparts) ? partials[t] : 0;
    s[t] = v;
    __syncthreads();
    for (int off = 1; off < 512; off <<= 1) {
        int tmp = (t >= off) ? s[t - off] : 0;
        __syncthreads();
        s[t] += tmp;
        __syncthreads();
    }
    if (t < nparts) partials[t] = s[t] - v;
    if (t == 511) row_start[n_nodes] = s[511];
}

__global__ void scan_pass3_kernel(const int* __restrict__ cnt, const int* __restrict__ partials,
                                  int* __restrict__ row_start, int* __restrict__ cursor, int n) {
    __shared__ int s[256];
    int i = blockIdx.x * 256 + threadIdx.x;
    int t = threadIdx.x;
    int v = (i < n) ? cnt[i] : 0;
    s[t] = v;
    __syncthreads();
    for (int off = 1; off < 256; off <<= 1) {
        int tmp = (t >= off) ? s[t - off] : 0;
        __syncthreads();
        s[t] += tmp;
        __syncthreads();
    }
    if (i < n) {
        int start = partials[blockIdx.x] + s[t] - v;
        row_start[i] = start;
        cursor[i] = start;
    }
}

__global__ void csr_fill_kernel(const int* __restrict__ row, const int* __restrict__ col,
                                const float* __restrict__ dinv, int* __restrict__ cursor,
                                int2* __restrict__ csr, int e) {
    int i = blockIdx.x * blockDim.x + threadIdx.x;
    if (i >= e) return;
    int r = row[i];
    int c = col[i];
    float w = dinv[r] * dinv[c];
    int pos = atomicAdd(&cursor[c], 1);
    csr[pos] = make_int2(r, __float_as_int(w));
}

// ================= linear: y0 = x @ W^T (no bias) =================
// W row o=lane held in 24 float4 VGPRs per lane; x staged in LDS, broadcast reads.

__global__ __launch_bounds__(256, 4) void linear_kernel(
        const float* __restrict__ x, const float* __restrict__ W,
        float* __restrict__ y, int n) {
    __shared__ float xs[NPB * IN_C];   // 24 KB

    int lane = threadIdx.x & 63;
    int wv = threadIdx.x >> 6;         // wave 0..3

    // per-lane weight row: W[lane][0..95] as 24 float4 (L1-resident, 24 KB total)
    const float4* Wrow = (const float4*)(W + (size_t)lane * IN_C);
    float4 wreg[24];
#pragma unroll
    for (int i = 0; i < 24; ++i) wreg[i] = Wrow[i];

    int node0 = blockIdx.x * NPB;
    // cooperative coalesced stage of x: NPB*96/4 = 1536 float4
    const float4* xg = (const float4*)(x + (size_t)node0 * IN_C);
    float4* xs4 = (float4*)xs;
    int avail4 = (n - node0) * (IN_C / 4);            // float4s actually present
    if (avail4 > NPB * (IN_C / 4)) avail4 = NPB * (IN_C / 4);
    for (int i = threadIdx.x; i < NPB * (IN_C / 4); i += 256) {
        xs4[i] = (i < avail4) ? xg[i] : make_float4(0.f, 0.f, 0.f, 0.f);
    }
    __syncthreads();

    // each wave computes 16 nodes; lane = output channel
#pragma unroll 1
    for (int k = 0; k < NPB / 4; ++k) {
        int nl = wv * (NPB / 4) + k;
        int node = node0 + nl;
        if (node >= n) break;
        const float4* xr = (const float4*)(xs + nl * IN_C);
        float acc = 0.0f;
#pragma unroll
        for (int c4 = 0; c4 < 24; ++c4) {
            float4 xv = xr[c4];        // wave-broadcast ds_read_b128
            acc += xv.x * wreg[c4].x + xv.y * wreg[c4].y
                 + xv.z * wreg[c4].z + xv.w * wreg[c4].w;
        }
        y[(size_t)node * OUT_C + lane] = acc;
    }
}

// ================= gather hop: one wave per node, lane = channel =================

template <bool FINAL>
__global__ void gather_kernel(const float* __restrict__ src, float* __restrict__ dst,
                              const int* __restrict__ row_start, const int2* __restrict__ csr,
                              const float* __restrict__ dinv, const float* __restrict__ bias,
                              int n) {
    int node = blockIdx.x * (blockDim.x >> 6) + (threadIdx.x >> 6);
    if (node >= n) return;
    int ch = threadIdx.x & 63;

    float s = dinv[node];
    float acc0 = s * s * src[(size_t)node * OUT_C + ch];
    float acc1 = 0.0f;

    int beg = row_start[node];
    int end = row_start[node + 1];
    int j = beg;
    for (; j + 1 < end; j += 2) {
        int2 p0 = csr[j];
        int2 p1 = csr[j + 1];
        float v0 = src[(size_t)p0.x * OUT_C + ch];
        float v1 = src[(size_t)p1.x * OUT_C + ch];
        acc0 += __int_as_float(p0.y) * v0;
        acc1 += __int_as_float(p1.y) * v1;
    }
    if (j < end) {
        int2 p = csr[j];
        acc0 += __int_as_float(p.y) * src[(size_t)p.x * OUT_C + ch];
    }
    float acc = acc0 + acc1;
    if (FINAL) {
        acc += bias[ch];
        acc = 1.0f / (1.0f + __expf(-acc));
    }
    dst[(size_t)node * OUT_C + ch] = acc;
}

// ================= launch =================

static inline size_t align16(size_t x) { return (x + 15) & ~(size_t)15; }

extern "C" void kernel_launch(void* const* d_in, const int* in_sizes, int n_in,
                              void* d_out, int out_size, void* d_ws, size_t ws_size,
                              hipStream_t stream) {
    const float* x = (const float*)d_in[0];
    const int* edge_index = (const int*)d_in[1];
    const float* W = (const float*)d_in[2];
    const float* b = (const float*)d_in[3];
    float* out = (float*)d_out;

    const int N = N_NODES;
    const int E = in_sizes[1] / 2;

    const int* row = edge_index;        // source
    const int* col = edge_index + E;    // destination

    char* ws = (char*)d_ws;
    size_t off = 0;
    int* cnt = (int*)(ws + off);        off = align16(off + (size_t)N * 4);
    float* dinv = (float*)(ws + off);   off = align16(off + (size_t)N * 4);
    int* row_start = (int*)(ws + off);  off = align16(off + (size_t)(N + 1) * 4);
    int* cursor = (int*)(ws + off);     off = align16(off + (size_t)N * 4);
    int* partials = (int*)(ws + off);   off = align16(off + 512 * 4);
    int2* csr = (int2*)(ws + off);      off = align16(off + (size_t)E * 8);
    float* y0 = (float*)(ws + off);     off = align16(off + (size_t)N * OUT_C * 4);
    float* y1 = (float*)(ws + off);     off = align16(off + (size_t)N * OUT_C * 4);

    const int B = 256;
    const int nb_n = (N + B - 1) / B;
    const int nb_e = (E + B - 1) / B;

    // ---- CSR build ----
    zero_int_kernel<<<nb_n, B, 0, stream>>>(cnt, N);
    count_kernel<<<nb_e, B, 0, stream>>>(col, cnt, E);
    dinv_kernel<<<nb_n, B, 0, stream>>>(cnt, dinv, N);
    scan_pass1_kernel<<<nb_n, B, 0, stream>>>(cnt, partials, N);
    scan_pass2_kernel<<<1, 512, 0, stream>>>(partials, row_start, nb_n, N);
    scan_pass3_kernel<<<nb_n, B, 0, stream>>>(cnt, partials, row_start, cursor, N);
    csr_fill_kernel<<<nb_e, B, 0, stream>>>(row, col, dinv, cursor, csr, E);

    // ---- linear first (propagation commutes with W): y0 = x @ W^T ----
    linear_kernel<<<(N + NPB - 1) / NPB, B, 0, stream>>>(x, W, y0, N);

    // ---- hop 1 ----
    gather_kernel<false><<<(N + 3) / 4, B, 0, stream>>>(y0, y1, row_start, csr, dinv, b, N);

    // ---- hop 2 + bias + sigmoid ----
    gather_kernel<true><<<(N + 3) / 4, B, 0, stream>>>(y1, out, row_start, csr, dinv, b, N);
}